// Round 2
// baseline (54.898 us; speedup 1.0000x reference)
//
#include <hip/hip_runtime.h>
#include <hip/hip_bf16.h>
#include <cstdint>

#define HW 112
#define NPIX (HW*HW)   // 12544
#define NB 2
#define NC 4
#define HD_GRID (12*HW)  // 1344 blocks

// ws layout (floats at base):
//   [0..11]   per-(b,dir,class) distance sums
//   [12..23]  per-(b,dir,class) point counts
//   [24]      completion counter (as uint bits; 0.0f == 0u)
//   +256:     packed masks  uint64_t[12 masks][112 rows][2 words]
//   +256+21504: g planes    uint8_t[12 planes][12544]
// mask id = b*6 + m, m=0..2 -> A(j=m+1) (argmax==j), m=3..5 -> B(j=m-2) (label==1)

__global__ __launch_bounds__(128) void prep_kernel(
    const float* __restrict__ pred, const int* __restrict__ labels,
    float* __restrict__ accum, unsigned long long* __restrict__ masks,
    unsigned char* __restrict__ gbuf)
{
  int blk = blockIdx.x;
  int b = blk / HW, r = blk % HW;
  int tid = threadIdx.x;
  int lane = tid & 63, wave = tid >> 6;
  int c = tid;

  if (blk == 0 && tid < 32) accum[tid] = 0.f;   // zero sums, counts, counter

  int cls = 255;
  if (c < HW) {
    const float* p0 = pred + ((size_t)(b*NC)*HW + r)*HW + c;
    float best = p0[0]; cls = 0;
    #pragma unroll
    for (int ch = 1; ch < NC; ch++) {
      float v = p0[(size_t)ch*NPIX];
      if (v > best) { best = v; cls = ch; }   // strict > : first-index tie-break like argmax
    }
  }

  __shared__ unsigned long long sm[6][2];
  #pragma unroll
  for (int m = 0; m < 3; m++) {
    bool p = (c < HW) && (cls == m + 1);
    unsigned long long bal = __ballot(p);
    if (lane == 0) sm[m][wave] = bal;
  }
  #pragma unroll
  for (int m = 0; m < 3; m++) {
    int lab = (c < HW) ? labels[((size_t)(b*NC + (m+1))*HW + r)*HW + c] : 0;
    bool p = (c < HW) && (lab == 1);
    unsigned long long bal = __ballot(p);
    if (lane == 0) sm[3 + m][wave] = bal;
  }
  __syncthreads();

  if (tid < 12) {
    int m = tid >> 1, w = tid & 1;
    masks[((size_t)(b*6 + m)*HW + r)*2 + w] = sm[m][w];
  }

  // phase 1: horizontal nearest-set-pixel distance, O(1)/pixel via clz/ffs
  for (int item = tid; item < 6*HW; item += 128) {
    int m = item / HW, cc = item % HW;
    unsigned long long lo = sm[m][0], hi = sm[m][1];
    int left, right;
    if (cc < 64) {
      unsigned long long wl = lo & ((2ull << cc) - 1);           // bits 0..cc
      left = wl ? 63 - __clzll(wl) : -1000;
      unsigned long long wr = lo & ~((1ull << cc) - 1);          // bits cc..63
      right = wr ? __ffsll(wr) - 1 : (hi ? 64 + __ffsll(hi) - 1 : 1000);
    } else {
      int cl = cc - 64;
      unsigned long long wl = hi & ((2ull << cl) - 1);           // bits 64..cc
      left = wl ? 64 + 63 - __clzll(wl) : (lo ? 63 - __clzll(lo) : -1000);
      unsigned long long wr = hi & ~((1ull << cl) - 1);          // bits cc..111
      right = wr ? 64 + __ffsll(wr) - 1 : 1000;
    }
    int gv = min(cc - left, right - cc);
    gv = min(gv, 255);  // 255 = "row empty" sentinel; 255^2 > max real d^2 = 24642
    gbuf[(size_t)(b*6 + m)*NPIX + r*HW + cc] = (unsigned char)gv;
  }
}

// one block per (pair-dir, row): phase-2 vertical min + masked sum/count reduce.
// The LAST block to finish (device-scope counter) performs the finalize and
// writes the 18 outputs — saves a third kernel launch.
__global__ __launch_bounds__(128) void hd_kernel(
    const unsigned long long* __restrict__ masks,
    const unsigned char* __restrict__ gbuf,
    float* __restrict__ accum, float* __restrict__ out)
{
  int blk = blockIdx.x;
  int pd = blk / HW, r = blk % HW;
  int b = pd / 6, k = pd % 6;
  // k<3: fwd for j=k+1 (src plane = B mask, target = A mask)
  // k>=3: rev for j=k-2 (src plane = A mask, target = B mask)
  int src = b*6 + (k + 3) % 6;
  int tgt = b*6 + k;
  int tid = threadIdx.x, lane = tid & 63, wave = tid >> 6, c = tid;

  bool inT = false;
  float val = 0.f;
  if (c < HW) {
    unsigned long long w = masks[((size_t)tgt*HW + r)*2 + (c >> 6)];
    inT = (w >> (c & 63)) & 1ull;
    const unsigned char* gp = gbuf + (size_t)src*NPIX + c;
    int mind = 0x7fffffff;
    #pragma unroll 8
    for (int rp = 0; rp < HW; rp++) {
      int gg = gp[(size_t)rp*HW];
      int dr = r - rp;
      int d = dr*dr + gg*gg;
      mind = min(mind, d);
    }
    val = inT ? sqrtf((float)mind) : 0.f;
  }

  unsigned long long bal = __ballot(inT);
  float s = val;
  #pragma unroll
  for (int off = 32; off; off >>= 1) s += __shfl_down(s, off, 64);
  __shared__ float ssum[2];
  __shared__ int scnt[2];
  __shared__ int isLast;
  if (lane == 0) { ssum[wave] = s; scnt[wave] = __popcll(bal); }
  __syncthreads();
  if (tid == 0) {
    atomicAdd(&accum[pd], ssum[0] + ssum[1]);
    atomicAdd(&accum[12 + pd], (float)(scnt[0] + scnt[1]));
    __threadfence();
    unsigned old = atomicAdd((unsigned int*)(accum + 24), 1u);
    isLast = (old == (unsigned)(HD_GRID - 1)) ? 1 : 0;
  }
  __syncthreads();

  if (isLast) {
    // coherent parallel read-back of the 24 accumulators via atomic RMW
    __shared__ float sacc[24];
    if (tid < 24) sacc[tid] = atomicAdd(&accum[tid], 0.0f);
    __syncthreads();
    if (tid == 0) {
      float mhd[6], fhd[6], rhd[6];
      for (int i = 0; i < 6; i++) { mhd[i] = 0.f; fhd[i] = 0.f; rhd[i] = 0.f; }
      for (int bb = 0; bb < 2; bb++)
        for (int j = 1; j < 4; j++) {
          int pf = bb*6 + (j - 1);
          int pr = bb*6 + 3 + (j - 1);
          float fwd = sacc[pf] / sacc[12 + pf];
          float rev = sacc[pr] / sacc[12 + pr];
          fhd[j] += fwd; rhd[j] += rev; mhd[j] += fmaxf(fwd, rev);
        }
      float* arrs[3] = { mhd, fhd, rhd };
      for (int a = 0; a < 3; a++) {
        float* x = arrs[a];
        for (int i = 0; i < 4; i++) x[i] *= 0.5f;          // /N
        x[4] = (x[0] + x[1] + x[2] + x[3]) * 0.25f;        // mean(x[:C])
        x[5] = (x[1] + x[2] + x[3]) * (1.f / 3.f);         // mean(x[1:C])
        for (int i = 0; i < 6; i++) out[a*6 + i] = x[i];
      }
    }
  }
}

extern "C" void kernel_launch(void* const* d_in, const int* in_sizes, int n_in,
                              void* d_out, int out_size, void* d_ws, size_t ws_size,
                              hipStream_t stream) {
  const float* pred = (const float*)d_in[0];
  const int* labels = (const int*)d_in[1];
  float* out = (float*)d_out;

  float* accum = (float*)d_ws;
  unsigned long long* masks = (unsigned long long*)((char*)d_ws + 256);
  unsigned char* gbuf = (unsigned char*)((char*)d_ws + 256 + (size_t)12*HW*2*sizeof(unsigned long long));

  prep_kernel<<<NB*HW, 128, 0, stream>>>(pred, labels, accum, masks, gbuf);
  hd_kernel<<<HD_GRID, 128, 0, stream>>>(masks, gbuf, accum, out);
}

// Round 3
// 20.108 us; speedup vs baseline: 2.7302x; 2.7302x over previous
//
#include <hip/hip_runtime.h>
#include <hip/hip_bf16.h>
#include <cstdint>
#include <climits>

#define HW 112
#define NPIX (HW*HW)   // 12544
#define NB 2
#define NC 4
#define ROWS_PER_BLK 4
#define CHUNKS (HW/ROWS_PER_BLK)   // 28
#define HD_GRID (12*CHUNKS)        // 336

// ws layout:
//   +0:       packed masks  uint64_t[12 masks][112 rows][2 words]  (21504 B)
//   +21504:   g planes      uint8_t[12 planes][12544]              (150528 B)
//   +172032:  partials      float2[336]  (sum, count) per hd block
// mask id = b*6 + m, m=0..2 -> A(j=m+1) (argmax==j), m=3..5 -> B(j=m-2) (label==1)

__global__ __launch_bounds__(128) void prep_kernel(
    const float* __restrict__ pred, const int* __restrict__ labels,
    unsigned long long* __restrict__ masks, unsigned char* __restrict__ gbuf)
{
  int blk = blockIdx.x;
  int b = blk / HW, r = blk % HW;
  int tid = threadIdx.x;
  int lane = tid & 63, wave = tid >> 6;
  int c = tid;

  int cls = 255;
  if (c < HW) {
    const float* p0 = pred + ((size_t)(b*NC)*HW + r)*HW + c;
    float best = p0[0]; cls = 0;
    #pragma unroll
    for (int ch = 1; ch < NC; ch++) {
      float v = p0[(size_t)ch*NPIX];
      if (v > best) { best = v; cls = ch; }   // strict > : first-index tie-break like argmax
    }
  }

  __shared__ unsigned long long sm[6][2];
  #pragma unroll
  for (int m = 0; m < 3; m++) {
    bool p = (c < HW) && (cls == m + 1);
    unsigned long long bal = __ballot(p);
    if (lane == 0) sm[m][wave] = bal;
  }
  #pragma unroll
  for (int m = 0; m < 3; m++) {
    int lab = (c < HW) ? labels[((size_t)(b*NC + (m+1))*HW + r)*HW + c] : 0;
    bool p = (c < HW) && (lab == 1);
    unsigned long long bal = __ballot(p);
    if (lane == 0) sm[3 + m][wave] = bal;
  }
  __syncthreads();

  if (tid < 12) {
    int m = tid >> 1, w = tid & 1;
    masks[((size_t)(b*6 + m)*HW + r)*2 + w] = sm[m][w];
  }

  // phase 1: horizontal nearest-set-pixel distance, O(1)/pixel via clz/ffs
  for (int item = tid; item < 6*HW; item += 128) {
    int m = item / HW, cc = item % HW;
    unsigned long long lo = sm[m][0], hi = sm[m][1];
    int left, right;
    if (cc < 64) {
      unsigned long long wl = lo & ((2ull << cc) - 1);           // bits 0..cc
      left = wl ? 63 - __clzll(wl) : -1000;
      unsigned long long wr = lo & ~((1ull << cc) - 1);          // bits cc..63
      right = wr ? __ffsll(wr) - 1 : (hi ? 64 + __ffsll(hi) - 1 : 1000);
    } else {
      int cl = cc - 64;
      unsigned long long wl = hi & ((2ull << cl) - 1);           // bits 64..cc
      left = wl ? 64 + 63 - __clzll(wl) : (lo ? 63 - __clzll(lo) : -1000);
      unsigned long long wr = hi & ~((1ull << cl) - 1);          // bits cc..111
      right = wr ? 64 + __ffsll(wr) - 1 : 1000;
    }
    int gv = min(cc - left, right - cc);
    gv = min(gv, 255);  // 255 = "row empty" sentinel; 255^2 > max real d^2 = 24642
    gbuf[(size_t)(b*6 + m)*NPIX + r*HW + cc] = (unsigned char)gv;
  }
}

// one block per (pair-dir, 4-row chunk): stage source g-plane in LDS (coalesced
// dwordx4), brute-force vertical min for 4 rows per thread-column, masked
// sum/count, block reduce, ONE plain float2 store. No atomics, no fences.
__global__ __launch_bounds__(128) void hd_kernel(
    const unsigned long long* __restrict__ masks,
    const unsigned char* __restrict__ gbuf,
    float2* __restrict__ partial)
{
  int blk = blockIdx.x;
  int pd = blk / CHUNKS, chunk = blk % CHUNKS;
  int b = pd / 6, k = pd % 6;
  // k<3: fwd for j=k+1 (src plane = B mask, target = A mask)
  // k>=3: rev for j=k-2 (src plane = A mask, target = B mask)
  int src = b*6 + (k + 3) % 6;
  int tgt = pd;
  int tid = threadIdx.x, lane = tid & 63, wv = tid >> 6;
  int c = tid;
  int r0 = chunk * ROWS_PER_BLK;

  __shared__ __align__(16) unsigned char sg[NPIX];
  {
    const uint4* s4 = (const uint4*)(gbuf + (size_t)src*NPIX);
    uint4* d4 = (uint4*)sg;
    #pragma unroll
    for (int i = 0; i < 7; i++) {
      int idx = tid + i*128;
      if (idx < NPIX/16) d4[idx] = s4[idx];
    }
  }
  __syncthreads();

  float sum = 0.f; float cf = 0.f;
  if (c < HW) {
    int m0 = INT_MAX, m1 = INT_MAX, m2 = INT_MAX, m3 = INT_MAX;
    #pragma unroll 4
    for (int rp = 0; rp < HW; rp++) {
      int g = sg[rp*HW + c];
      int gsq = g*g;
      int dr = r0 - rp;
      m0 = min(m0, dr*dr + gsq);
      m1 = min(m1, (dr+1)*(dr+1) + gsq);
      m2 = min(m2, (dr+2)*(dr+2) + gsq);
      m3 = min(m3, (dr+3)*(dr+3) + gsq);
    }
    int mins[4] = { m0, m1, m2, m3 };
    #pragma unroll
    for (int i = 0; i < 4; i++) {
      unsigned long long wm = masks[((size_t)tgt*HW + (r0 + i))*2 + (c >> 6)];
      if ((wm >> (c & 63)) & 1ull) { sum += sqrtf((float)mins[i]); cf += 1.f; }
    }
  }

  #pragma unroll
  for (int off = 32; off; off >>= 1) {
    sum += __shfl_down(sum, off, 64);
    cf  += __shfl_down(cf, off, 64);
  }
  __shared__ float red[4];
  if (lane == 0) { red[wv*2] = sum; red[wv*2 + 1] = cf; }
  __syncthreads();
  if (tid == 0) partial[blk] = make_float2(red[0] + red[2], red[1] + red[3]);
}

// 12 waves, one per (b,dir,class): deterministic shuffle-reduce of 28 partials,
// then thread 0 finalizes the 18 outputs.
__global__ __launch_bounds__(768) void fin_kernel(
    const float2* __restrict__ partial, float* __restrict__ out)
{
  int tid = threadIdx.x;
  int w = tid >> 6, lane = tid & 63;
  __shared__ float sacc[24];

  float s = 0.f, cnt = 0.f;
  if (lane < CHUNKS) {
    float2 p = partial[w*CHUNKS + lane];
    s = p.x; cnt = p.y;
  }
  #pragma unroll
  for (int off = 32; off; off >>= 1) {
    s   += __shfl_down(s, off, 64);
    cnt += __shfl_down(cnt, off, 64);
  }
  if (lane == 0) { sacc[w] = s; sacc[12 + w] = cnt; }
  __syncthreads();

  if (tid == 0) {
    float mhd[6], fhd[6], rhd[6];
    for (int i = 0; i < 6; i++) { mhd[i] = 0.f; fhd[i] = 0.f; rhd[i] = 0.f; }
    for (int bb = 0; bb < 2; bb++)
      for (int j = 1; j < 4; j++) {
        int pf = bb*6 + (j - 1);
        int pr = bb*6 + 3 + (j - 1);
        float fwd = sacc[pf] / sacc[12 + pf];
        float rev = sacc[pr] / sacc[12 + pr];
        fhd[j] += fwd; rhd[j] += rev; mhd[j] += fmaxf(fwd, rev);
      }
    float* arrs[3] = { mhd, fhd, rhd };
    for (int a = 0; a < 3; a++) {
      float* x = arrs[a];
      for (int i = 0; i < 4; i++) x[i] *= 0.5f;          // /N
      x[4] = (x[0] + x[1] + x[2] + x[3]) * 0.25f;        // mean(x[:C])
      x[5] = (x[1] + x[2] + x[3]) * (1.f / 3.f);         // mean(x[1:C])
      for (int i = 0; i < 6; i++) out[a*6 + i] = x[i];
    }
  }
}

extern "C" void kernel_launch(void* const* d_in, const int* in_sizes, int n_in,
                              void* d_out, int out_size, void* d_ws, size_t ws_size,
                              hipStream_t stream) {
  const float* pred = (const float*)d_in[0];
  const int* labels = (const int*)d_in[1];
  float* out = (float*)d_out;

  unsigned long long* masks = (unsigned long long*)d_ws;
  unsigned char* gbuf = (unsigned char*)d_ws + 21504;
  float2* partial = (float2*)((char*)d_ws + 21504 + (size_t)12*NPIX);

  prep_kernel<<<NB*HW, 128, 0, stream>>>(pred, labels, masks, gbuf);
  hd_kernel<<<HD_GRID, 128, 0, stream>>>(masks, gbuf, partial);
  fin_kernel<<<1, 768, 0, stream>>>(partial, out);
}

// Round 4
// 18.564 us; speedup vs baseline: 2.9572x; 1.0831x over previous
//
#include <hip/hip_runtime.h>
#include <hip/hip_bf16.h>
#include <cstdint>
#include <climits>

#define HW 112
#define NPIX (HW*HW)   // 12544
#define NB 2
#define NC 4
#define CHUNKS 28                  // chunks per (pair,dir); 4 rows each
#define HD_GRID (12*CHUNKS)        // 336

// ws layout:
//   +0:       packed masks  uint64_t[12 masks][112 rows][2 words]   (21504 B)
//   +21504:   g^2 planes    uint16_t[12 planes][12544]              (301056 B)
//   +322560:  partials      float2[336]  (sum, count) per hd block
// mask id = b*6 + m, m=0..2 -> A(j=m+1) (argmax==j), m=3..5 -> B(j=m-2) (label==1)

__global__ __launch_bounds__(128) void prep_kernel(
    const float* __restrict__ pred, const int* __restrict__ labels,
    unsigned long long* __restrict__ masks, unsigned short* __restrict__ gsqbuf)
{
  int blk = blockIdx.x;
  int b = blk / HW, r = blk % HW;
  int tid = threadIdx.x;
  int lane = tid & 63, wave = tid >> 6;
  int c = tid;

  int cls = 255;
  if (c < HW) {
    const float* p0 = pred + ((size_t)(b*NC)*HW + r)*HW + c;
    float best = p0[0]; cls = 0;
    #pragma unroll
    for (int ch = 1; ch < NC; ch++) {
      float v = p0[(size_t)ch*NPIX];
      if (v > best) { best = v; cls = ch; }   // strict > : first-index tie-break like argmax
    }
  }

  __shared__ unsigned long long sm[6][2];
  #pragma unroll
  for (int m = 0; m < 3; m++) {
    bool p = (c < HW) && (cls == m + 1);
    unsigned long long bal = __ballot(p);
    if (lane == 0) sm[m][wave] = bal;
  }
  #pragma unroll
  for (int m = 0; m < 3; m++) {
    int lab = (c < HW) ? labels[((size_t)(b*NC + (m+1))*HW + r)*HW + c] : 0;
    bool p = (c < HW) && (lab == 1);
    unsigned long long bal = __ballot(p);
    if (lane == 0) sm[3 + m][wave] = bal;
  }
  __syncthreads();

  if (tid < 12) {
    int m = tid >> 1, w = tid & 1;
    masks[((size_t)(b*6 + m)*HW + r)*2 + w] = sm[m][w];
  }

  // phase 1: horizontal nearest-set-pixel distance, O(1)/pixel via clz/ffs;
  // store g^2 as ushort (saves a mul + byte-extract per hd inner iteration)
  for (int item = tid; item < 6*HW; item += 128) {
    int m = item / HW, cc = item % HW;
    unsigned long long lo = sm[m][0], hi = sm[m][1];
    int left, right;
    if (cc < 64) {
      unsigned long long wl = lo & ((2ull << cc) - 1);           // bits 0..cc
      left = wl ? 63 - __clzll(wl) : -1000;
      unsigned long long wr = lo & ~((1ull << cc) - 1);          // bits cc..63
      right = wr ? __ffsll(wr) - 1 : (hi ? 64 + __ffsll(hi) - 1 : 1000);
    } else {
      int cl = cc - 64;
      unsigned long long wl = hi & ((2ull << cl) - 1);           // bits 64..cc
      left = wl ? 64 + 63 - __clzll(wl) : (lo ? 63 - __clzll(lo) : -1000);
      unsigned long long wr = hi & ~((1ull << cl) - 1);          // bits cc..111
      right = wr ? 64 + __ffsll(wr) - 1 : 1000;
    }
    int gv = min(cc - left, right - cc);
    gv = min(gv, 255);  // 255 = "row empty" sentinel; 255^2 > max real d^2 = 24642
    gsqbuf[(size_t)(b*6 + m)*NPIX + r*HW + cc] = (unsigned short)(gv*gv);
  }
}

// one block per (pair-dir, 4-row chunk), 256 threads = 2 col-slices x 2 rows.
// Stage the src g^2 plane into LDS (coalesced dwordx4), vertical min with
// full-rate mad_i32_i24, masked sum/count, block reduce, one float2 store.
__global__ __launch_bounds__(256) void hd_kernel(
    const unsigned long long* __restrict__ masks,
    const unsigned short* __restrict__ gsqbuf,
    float2* __restrict__ partial)
{
  int blk = blockIdx.x;
  int pd = blk / CHUNKS, chunk = blk % CHUNKS;
  int b = pd / 6, k = pd % 6;
  // k<3: fwd for j=k+1 (src plane = B mask, target = A mask)
  // k>=3: rev for j=k-2 (src plane = A mask, target = B mask)
  int src = b*6 + (k + 3) % 6;
  int tid = threadIdx.x, lane = tid & 63, wv = tid >> 6;

  __shared__ __align__(16) unsigned short sgq[NPIX];
  {
    const uint4* s4 = (const uint4*)(gsqbuf + (size_t)src*NPIX);
    uint4* d4 = (uint4*)sgq;
    #pragma unroll
    for (int i = 0; i < 7; i++) {
      int idx = tid + i*256;
      if (idx < NPIX/8) d4[idx] = s4[idx];   // 25088 B = 1568 x uint4
    }
  }
  __syncthreads();

  int s = tid / HW;        // slice 0,1 active; tid>=224 idle
  int c = tid % HW;
  float sum = 0.f, cf = 0.f;
  if (s < 2) {
    int r0 = chunk*4 + 2*s;
    int m0 = INT_MAX, m1 = INT_MAX;
    #pragma unroll 4
    for (int rp = 0; rp < HW; rp++) {
      int g2 = sgq[rp*HW + c];
      int dr = r0 - rp;
      m0 = min(m0, __mul24(dr, dr) + g2);          // v_mad_i32_i24: full rate
      m1 = min(m1, __mul24(dr + 1, dr + 1) + g2);
    }
    unsigned long long w0 = masks[((size_t)pd*HW + r0)*2 + (c >> 6)];
    unsigned long long w1 = masks[((size_t)pd*HW + r0 + 1)*2 + (c >> 6)];
    if ((w0 >> (c & 63)) & 1ull) { sum += sqrtf((float)m0); cf += 1.f; }
    if ((w1 >> (c & 63)) & 1ull) { sum += sqrtf((float)m1); cf += 1.f; }
  }

  #pragma unroll
  for (int off = 32; off; off >>= 1) {
    sum += __shfl_down(sum, off, 64);
    cf  += __shfl_down(cf, off, 64);
  }
  __shared__ float red[8];
  if (lane == 0) { red[wv*2] = sum; red[wv*2 + 1] = cf; }
  __syncthreads();
  if (tid == 0)
    partial[blk] = make_float2(red[0] + red[2] + red[4] + red[6],
                               red[1] + red[3] + red[5] + red[7]);
}

// 12 waves, one per (b,dir,class): deterministic shuffle-reduce of 28 partials,
// then thread 0 finalizes the 18 outputs.
__global__ __launch_bounds__(768) void fin_kernel(
    const float2* __restrict__ partial, float* __restrict__ out)
{
  int tid = threadIdx.x;
  int w = tid >> 6, lane = tid & 63;
  __shared__ float sacc[24];

  float s = 0.f, cnt = 0.f;
  if (lane < CHUNKS) {
    float2 p = partial[w*CHUNKS + lane];
    s = p.x; cnt = p.y;
  }
  #pragma unroll
  for (int off = 32; off; off >>= 1) {
    s   += __shfl_down(s, off, 64);
    cnt += __shfl_down(cnt, off, 64);
  }
  if (lane == 0) { sacc[w] = s; sacc[12 + w] = cnt; }
  __syncthreads();

  if (tid == 0) {
    float mhd[6], fhd[6], rhd[6];
    for (int i = 0; i < 6; i++) { mhd[i] = 0.f; fhd[i] = 0.f; rhd[i] = 0.f; }
    for (int bb = 0; bb < 2; bb++)
      for (int j = 1; j < 4; j++) {
        int pf = bb*6 + (j - 1);
        int pr = bb*6 + 3 + (j - 1);
        float fwd = sacc[pf] / sacc[12 + pf];
        float rev = sacc[pr] / sacc[12 + pr];
        fhd[j] += fwd; rhd[j] += rev; mhd[j] += fmaxf(fwd, rev);
      }
    float* arrs[3] = { mhd, fhd, rhd };
    for (int a = 0; a < 3; a++) {
      float* x = arrs[a];
      for (int i = 0; i < 4; i++) x[i] *= 0.5f;          // /N
      x[4] = (x[0] + x[1] + x[2] + x[3]) * 0.25f;        // mean(x[:C])
      x[5] = (x[1] + x[2] + x[3]) * (1.f / 3.f);         // mean(x[1:C])
      for (int i = 0; i < 6; i++) out[a*6 + i] = x[i];
    }
  }
}

extern "C" void kernel_launch(void* const* d_in, const int* in_sizes, int n_in,
                              void* d_out, int out_size, void* d_ws, size_t ws_size,
                              hipStream_t stream) {
  const float* pred = (const float*)d_in[0];
  const int* labels = (const int*)d_in[1];
  float* out = (float*)d_out;

  unsigned long long* masks = (unsigned long long*)d_ws;
  unsigned short* gsqbuf = (unsigned short*)((char*)d_ws + 21504);
  float2* partial = (float2*)((char*)d_ws + 21504 + (size_t)12*NPIX*sizeof(unsigned short));

  prep_kernel<<<NB*HW, 128, 0, stream>>>(pred, labels, masks, gsqbuf);
  hd_kernel<<<HD_GRID, 256, 0, stream>>>(masks, gsqbuf, partial);
  fin_kernel<<<1, 768, 0, stream>>>(partial, out);
}